// Round 5
// baseline (807.773 us; speedup 1.0000x reference)
//
#include <hip/hip_runtime.h>

// ---------------- problem constants ----------------
#define T_TOK 8192      // B*S tokens
#define DDIM  1024
#define NEXP  8
#define FDIM  4096
#define BM    128       // GEMM tile M=N
#define BK    32        // GEMM K-step (ring-3 counted-vmcnt schedule)
#define SLOT_CAP (T_TOK*2 + NEXP*BM)   // 17408 padded (token,expert) slots

using short8  = __attribute__((ext_vector_type(8))) short;   // 8 bf16 (A/B frag)
using floatx4 = __attribute__((ext_vector_type(4))) float;   // C/D frag

__device__ __forceinline__ unsigned short f32_to_bf16(float f) {
    unsigned int u = __float_as_uint(f);
    u = (u + 0x7FFFu + ((u >> 16) & 1u)) >> 16;   // RTNE
    return (unsigned short)u;
}

// ---------------- router: logits -> top2 -> gates ; also x->bf16 ----------------
__global__ void router_kernel(const float* __restrict__ x, const float* __restrict__ gw,
                              int* __restrict__ tk_e, float* __restrict__ tk_g,
                              unsigned short* __restrict__ xb) {
    const int wave = threadIdx.x >> 6, lane = threadIdx.x & 63;
    const int t = blockIdx.x * 4 + wave;
    const float* xr = x + (size_t)t * DDIM;
    unsigned short* xbr = xb + (size_t)t * DDIM;
    float acc[8] = {0.f,0.f,0.f,0.f,0.f,0.f,0.f,0.f};
    for (int i = lane; i < DDIM; i += 64) {
        float xv = xr[i];
        xbr[i] = f32_to_bf16(xv);                 // fused fp32->bf16 (coalesced 2B/lane)
        const float4* g4 = (const float4*)(gw + i * NEXP);
        float4 a = g4[0], b = g4[1];
        acc[0] += xv*a.x; acc[1] += xv*a.y; acc[2] += xv*a.z; acc[3] += xv*a.w;
        acc[4] += xv*b.x; acc[5] += xv*b.y; acc[6] += xv*b.z; acc[7] += xv*b.w;
    }
    #pragma unroll
    for (int s = 32; s > 0; s >>= 1)
        #pragma unroll
        for (int e = 0; e < 8; ++e)
            acc[e] += __shfl_xor(acc[e], s, 64);
    if (lane == 0) {
        int e0 = 0; float v0 = acc[0];
        #pragma unroll
        for (int e = 1; e < 8; ++e) if (acc[e] > v0) { v0 = acc[e]; e0 = e; }
        int e1 = -1; float v1 = -1e30f;
        #pragma unroll
        for (int e = 0; e < 8; ++e) if (e != e0 && acc[e] > v1) { v1 = acc[e]; e1 = e; }
        float g0 = 1.0f / (1.0f + expf(v1 - v0));  // renormalized top-2 softmax
        tk_e[t*2] = e0;  tk_e[t*2+1] = e1;
        tk_g[t*2] = g0;  tk_g[t*2+1] = 1.0f - g0;
    }
}

// ---------------- fused count + scan + scatter + pad-fill (single block) ----------------
__global__ void sortscatter_kernel(const int* __restrict__ tk_e, int* __restrict__ offsets,
                                   int* __restrict__ perm_token, int* __restrict__ tok2slot) {
    __shared__ int cnt[NEXP];
    __shared__ int off_s[NEXP + 1];
    __shared__ int cur[NEXP];
    const int tid = threadIdx.x;
    if (tid < NEXP) cnt[tid] = 0;
    __syncthreads();
    for (int i = tid; i < 2 * T_TOK; i += 1024)
        atomicAdd(&cnt[tk_e[i]], 1);
    __syncthreads();
    if (tid == 0) {
        int o = 0;
        for (int e = 0; e < NEXP; ++e) {
            off_s[e] = o; cur[e] = 0;
            o += (cnt[e] + BM - 1) & ~(BM - 1);
        }
        off_s[NEXP] = o;
    }
    __syncthreads();
    if (tid <= NEXP) offsets[tid] = off_s[tid];
    for (int i = tid; i < 2 * T_TOK; i += 1024) {
        int e = tk_e[i];
        int slot = off_s[e] + atomicAdd(&cur[e], 1);
        perm_token[slot] = i >> 1;
        tok2slot[i] = slot;
    }
    __syncthreads();
    // pad slots -> token 0 (their outputs are never gathered by combine)
    #pragma unroll
    for (int e = 0; e < NEXP; ++e) {
        int base = off_s[e] + cnt[e];
        int pad  = off_s[e + 1] - base;
        for (int i = tid; i < pad; i += 1024) perm_token[base + i] = 0;
    }
}

// ---------------- fused transpose + fp32->bf16 for BOTH weights ----------------
__global__ void transpose_cvt2_kernel(const float* __restrict__ w1, const float* __restrict__ w2,
                                      unsigned short* __restrict__ w1T, unsigned short* __restrict__ w2T) {
    const int z = blockIdx.y;
    const bool is1 = z < NEXP;
    const int e = is1 ? z : z - NEXP;
    const int C = is1 ? FDIM : DDIM;
    const int cshift = is1 ? 6 : 4;                // tiles along C = C/64
    const int R = is1 ? DDIM : FDIM;
    const float* w = (is1 ? w1 : w2) + (size_t)e * DDIM * FDIM;
    unsigned short* o = (is1 ? w1T : w2T) + (size_t)e * DDIM * FDIM;
    const int t = blockIdx.x;                      // 1024 tiles per expert
    const int c0 = (t & ((C >> 6) - 1)) * 64, r0 = (t >> cshift) * 64;
    __shared__ float tile[64][65];
    const int l = threadIdx.x & 15, row = threadIdx.x >> 4;   // 16 x 16
    #pragma unroll
    for (int j = 0; j < 4; ++j) {
        int r = row + j * 16;
        float4 v = *(const float4*)(w + (size_t)(r0 + r) * C + c0 + l * 4);
        tile[r][l*4+0] = v.x; tile[r][l*4+1] = v.y; tile[r][l*4+2] = v.z; tile[r][l*4+3] = v.w;
    }
    __syncthreads();
    #pragma unroll
    for (int j = 0; j < 4; ++j) {
        int c = row + j * 16;
        ushort4 v;
        v.x = f32_to_bf16(tile[l*4+0][c]);
        v.y = f32_to_bf16(tile[l*4+1][c]);
        v.z = f32_to_bf16(tile[l*4+2][c]);
        v.w = f32_to_bf16(tile[l*4+3][c]);
        *(ushort4*)(o + (size_t)(c0 + c) * R + r0 + l * 4) = v;
    }
}

// ============ ring-3 counted-vmcnt GEMM pieces (T3-lite + T4) ============
// Tile 128(M)x128(N), BK=32. 256 threads = 4 waves (2Mx2N), per-wave C 64x64.
// LDS: 3 ring slots x (A 128x32 + B 128x32) bf16 = 48 KiB -> 3 blocks/CU.
// Schedule (1 barrier / K-step, vmcnt never 0 in-loop):
//   iter t: vmcnt(4) [own tile-t loads done] ; s_barrier [all waves' tile-t
//   done + slot (t-1)%3 free] ; STAGE tile t+2 -> slot (t-1)%3 ; COMPUTE slot t%3.
// 4 gloads/tile/wave => gate vmcnt(4) leaves tile t+1 in flight (T4).
// Swizzle (64B rows, 4x16B granules): LDS[m][g] = global[m][g ^ ((m>>1)&3)].
// ds_read: 64 lanes cover 16 rows x 4 granules bijectively (1024B region,
// every bank word once) -> conflict-free, same argument as the measured-0
// round-2 pattern.

#define STAGE2(AD, BD, KOFF) do {                                                           \
    _Pragma("unroll")                                                                       \
    for (int r_ = 0; r_ < 2; ++r_) {                                                        \
        __builtin_amdgcn_global_load_lds(                                                   \
            (const __attribute__((address_space(1))) void*)(aptr[r_] + (KOFF)),             \
            (__attribute__((address_space(3))) void*)((char*)(AD) + (r_ * 64 + wave * 16) * 64), \
            16, 0, 0);                                                                      \
        __builtin_amdgcn_global_load_lds(                                                   \
            (const __attribute__((address_space(1))) void*)(bptr[r_] + (KOFF)),             \
            (__attribute__((address_space(3))) void*)((char*)(BD) + (r_ * 64 + wave * 16) * 64), \
            16, 0, 0);                                                                      \
    } } while (0)

#define COMPUTE2(AD, BD) do {                                                               \
    short8 af[4], bfr[4];                                                                   \
    _Pragma("unroll")                                                                       \
    for (int im = 0; im < 4; ++im) {                                                        \
        int m = wm * 64 + im * 16 + l15;                                                    \
        af[im] = *(const short8*)((const char*)(AD) + m * 64 + ((quad ^ ((l15 >> 1) & 3)) << 4)); \
    }                                                                                       \
    _Pragma("unroll")                                                                       \
    for (int in = 0; in < 4; ++in) {                                                        \
        int n = wn * 64 + in * 16 + l15;                                                    \
        bfr[in] = *(const short8*)((const char*)(BD) + n * 64 + ((quad ^ ((l15 >> 1) & 3)) << 4)); \
    }                                                                                       \
    _Pragma("unroll")                                                                       \
    for (int im = 0; im < 4; ++im)                                                          \
        _Pragma("unroll")                                                                   \
        for (int in = 0; in < 4; ++in)                                                      \
            acc[im][in] = __builtin_amdgcn_mfma_f32_16x16x32_bf16(af[im], bfr[in], acc[im][in], 0, 0, 0); \
    } while (0)

#define GEMM_RING_LOOP(NT) do {                                                             \
    STAGE2(&As[0][0], &Bs[0][0], 0);                                                        \
    STAGE2(&As[1][0], &Bs[1][0], BK);                                                       \
    int s0 = 0, s1 = 1, s2 = 2;                                                             \
    _Pragma("unroll 1")                                                                     \
    for (int t = 0; t < (NT) - 1; ++t) {                                                    \
        asm volatile("s_waitcnt vmcnt(4)" ::: "memory");                                    \
        __builtin_amdgcn_s_barrier();                                                       \
        if (t + 2 < (NT)) STAGE2(&As[s2][0], &Bs[s2][0], (t + 2) * BK);                     \
        COMPUTE2(&As[s0][0], &Bs[s0][0]);                                                   \
        int tmp = s0; s0 = s1; s1 = s2; s2 = tmp;                                           \
    }                                                                                       \
    asm volatile("s_waitcnt vmcnt(0)" ::: "memory");                                        \
    __builtin_amdgcn_s_barrier();                                                           \
    COMPUTE2(&As[s0][0], &Bs[s0][0]);                                                       \
} while (0)

// ---------------- GEMM1: h = gelu(x[perm] @ w1[e] + b1[e]), bf16 out ----------------
// XCD-grouped 1-D grid: all 32 N-blocks of an M-tile share p%8 (same XCD).
__global__ __launch_bounds__(256, 3) void gemm1_kernel(
    const unsigned short* __restrict__ xb, const unsigned short* __restrict__ w1T,
    const float* __restrict__ b1, const int* __restrict__ perm_token,
    const int* __restrict__ offsets, unsigned short* __restrict__ h) {
    __shared__ __align__(16) unsigned short As[3][BM * BK];
    __shared__ __align__(16) unsigned short Bs[3][BM * BK];
    const int p = blockIdx.x;
    const int q = p >> 3;
    const int nt = q & 31;                          // 32 N-tiles
    const int mt = ((q >> 5) << 3) | (p & 7);       // 136 M-tiles, grouped by XCD
    const int row0 = mt * BM;
    if (row0 >= offsets[NEXP]) return;
    const int n0 = nt * BM;
    int e = 0;
    while (e < NEXP - 1 && offsets[e + 1] <= row0) ++e;
    const int lane = threadIdx.x & 63, wave = threadIdx.x >> 6;
    const int srow = lane >> 2;                     // 16 rows per wave per pass
    const int scol = (lane & 3) ^ ((lane >> 3) & 3);  // inverse swizzle on global side
    const unsigned short* aptr[2];
    const unsigned short* bptr[2];
    #pragma unroll
    for (int r = 0; r < 2; ++r) {
        int arow = r * 64 + wave * 16 + srow;
        int tok = perm_token[row0 + arow];
        aptr[r] = xb + (size_t)tok * DDIM + scol * 8;
        int brow = n0 + r * 64 + wave * 16 + srow;
        bptr[r] = w1T + ((size_t)e * FDIM + brow) * DDIM + scol * 8;
    }
    const int wm = wave >> 1, wn = wave & 1;
    const int l15 = lane & 15, quad = lane >> 4;
    floatx4 acc[4][4];
    #pragma unroll
    for (int im = 0; im < 4; ++im)
        #pragma unroll
        for (int in = 0; in < 4; ++in)
            acc[im][in] = (floatx4){0.f, 0.f, 0.f, 0.f};

    GEMM_RING_LOOP(DDIM / BK);

    // epilogue: bias + tanh-gelu -> bf16 h
    #pragma unroll
    for (int im = 0; im < 4; ++im) {
        int mbase = row0 + wm * 64 + im * 16 + quad * 4;
        #pragma unroll
        for (int r = 0; r < 4; ++r) {
            #pragma unroll
            for (int in = 0; in < 4; ++in) {
                int n = n0 + wn * 64 + in * 16 + l15;
                float z = acc[im][in][r] + b1[e * FDIM + n];
                float u = __expf(1.5957691216057308f * (z + 0.044715f * z * z * z));
                float t = 1.0f - __fdividef(2.0f, u + 1.0f);     // tanh
                float g = 0.5f * z * (1.0f + t);
                h[(size_t)(mbase + r) * FDIM + n] = f32_to_bf16(g);
            }
        }
    }
}

// ---------------- GEMM2: y[slot] = h[slot] @ w2[e] + b2[e]  (fp32, no gate) ----------------
__global__ __launch_bounds__(256, 3) void gemm2_kernel(
    const unsigned short* __restrict__ h, const unsigned short* __restrict__ w2T,
    const float* __restrict__ b2, const int* __restrict__ offsets,
    float* __restrict__ y) {
    __shared__ __align__(16) unsigned short As[3][BM * BK];
    __shared__ __align__(16) unsigned short Bs[3][BM * BK];
    const int p = blockIdx.x;
    const int q = p >> 3;
    const int nt = q & 7;                           // 8 N-tiles
    const int mt = ((q >> 3) << 3) | (p & 7);       // 136 M-tiles, grouped by XCD
    const int row0 = mt * BM;
    if (row0 >= offsets[NEXP]) return;
    const int n0 = nt * BM;
    int e = 0;
    while (e < NEXP - 1 && offsets[e + 1] <= row0) ++e;
    const int lane = threadIdx.x & 63, wave = threadIdx.x >> 6;
    const int srow = lane >> 2;
    const int scol = (lane & 3) ^ ((lane >> 3) & 3);
    const unsigned short* aptr[2];
    const unsigned short* bptr[2];
    #pragma unroll
    for (int r = 0; r < 2; ++r) {
        int arow = r * 64 + wave * 16 + srow;
        aptr[r] = h + (size_t)(row0 + arow) * FDIM + scol * 8;
        int brow = n0 + r * 64 + wave * 16 + srow;
        bptr[r] = w2T + ((size_t)e * DDIM + brow) * FDIM + scol * 8;
    }
    const int wm = wave >> 1, wn = wave & 1;
    const int l15 = lane & 15, quad = lane >> 4;
    floatx4 acc[4][4];
    #pragma unroll
    for (int im = 0; im < 4; ++im)
        #pragma unroll
        for (int in = 0; in < 4; ++in)
            acc[im][in] = (floatx4){0.f, 0.f, 0.f, 0.f};

    GEMM_RING_LOOP(FDIM / BK);

    // epilogue: bias, coalesced fp32 stores per slot (quad rows -> 64B lines)
    #pragma unroll
    for (int im = 0; im < 4; ++im) {
        int mbase = row0 + wm * 64 + im * 16 + quad * 4;
        #pragma unroll
        for (int r = 0; r < 4; ++r) {
            #pragma unroll
            for (int in = 0; in < 4; ++in) {
                int n = n0 + wn * 64 + in * 16 + l15;
                y[(size_t)(mbase + r) * DDIM + n] = acc[im][in][r] + b2[e * DDIM + n];
            }
        }
    }
}

// ---------------- combine: out[t] = g0*y[s0] + g1*y[s1] ----------------
__global__ void combine_kernel(const float* __restrict__ y, const int* __restrict__ tok2slot,
                               const float* __restrict__ tk_g, float* __restrict__ out) {
    const int t = blockIdx.x;
    const int s0 = tok2slot[2 * t], s1 = tok2slot[2 * t + 1];
    const float g0 = tk_g[2 * t], g1 = tk_g[2 * t + 1];
    float4 a = ((const float4*)(y + (size_t)s0 * DDIM))[threadIdx.x];
    float4 b = ((const float4*)(y + (size_t)s1 * DDIM))[threadIdx.x];
    float4 o;
    o.x = g0 * a.x + g1 * b.x;  o.y = g0 * a.y + g1 * b.y;
    o.z = g0 * a.z + g1 * b.z;  o.w = g0 * a.w + g1 * b.w;
    ((float4*)(out + (size_t)t * DDIM))[threadIdx.x] = o;
}

// ---------------- launch ----------------
extern "C" void kernel_launch(void* const* d_in, const int* in_sizes, int n_in,
                              void* d_out, int out_size, void* d_ws, size_t ws_size,
                              hipStream_t stream) {
    (void)in_sizes; (void)n_in; (void)ws_size; (void)out_size;
    const float* x  = (const float*)d_in[0];
    const float* gw = (const float*)d_in[1];
    const float* w1 = (const float*)d_in[2];
    const float* b1 = (const float*)d_in[3];
    const float* w2 = (const float*)d_in[4];
    const float* b2 = (const float*)d_in[5];
    float* out = (float*)d_out;

    char* ws = (char*)d_ws;
    size_t off = 0;
    unsigned short* xb  = (unsigned short*)(ws + off); off += (size_t)T_TOK * DDIM * 2;       // 16 MiB
    unsigned short* w1T = (unsigned short*)(ws + off); off += (size_t)NEXP * DDIM * FDIM * 2; // 64 MiB
    unsigned short* w2T = (unsigned short*)(ws + off); off += (size_t)NEXP * DDIM * FDIM * 2; // 64 MiB
    unsigned short* h   = (unsigned short*)(ws + off); off += (size_t)SLOT_CAP * FDIM * 2;    // 136 MiB
    // y (fp32, 68 MiB) overlays xb+w1T: both dead once gemm1 finished; gemm2/combine only
    float* y = (float*)d_ws;
    int*   meta       = (int*)(ws + off);
    int*   perm_token = meta;                          // SLOT_CAP (pads filled by sortscatter)
    int*   offsets    = meta + SLOT_CAP;               // 9
    int*   tk_e       = offsets + NEXP + 1;            // 2T
    float* tk_g       = (float*)(tk_e + 2 * T_TOK);    // 2T
    int*   tok2slot   = (int*)(tk_g + 2 * T_TOK);      // 2T

    router_kernel<<<T_TOK / 4, 256, 0, stream>>>(x, gw, tk_e, tk_g, xb);
    sortscatter_kernel<<<1, 1024, 0, stream>>>(tk_e, offsets, perm_token, tok2slot);
    dim3 gt(1024, 2 * NEXP);
    transpose_cvt2_kernel<<<gt, 256, 0, stream>>>(w1, w2, w1T, w2T);

    // XCD-grouped 1-D grids (decode in-kernel)
    gemm1_kernel<<<(SLOT_CAP / BM) * (FDIM / BM), 256, 0, stream>>>(xb, w1T, b1, perm_token, offsets, h);
    gemm2_kernel<<<(SLOT_CAP / BM) * (DDIM / BM), 256, 0, stream>>>(h, w2T, b2, offsets, y);
    combine_kernel<<<T_TOK, 256, 0, stream>>>(y, tok2slot, tk_g, out);
}